// Round 1
// baseline (885.077 us; speedup 1.0000x reference)
//
#include <hip/hip_runtime.h>
#include <hip/hip_bf16.h>

typedef __hip_bfloat16 bf16;

// ---------------------------------------------------------------------------
// Problem constants: B=128, C_IN=3, LAT=64, OUT=512, EMB=5, H=128
// Layer i: dwconv(dynamic per-sample kernel) -> channel mix -> lrelu -> BN
// BN folded forward: layer stores pre-BN activation (bf16) + per-channel
// sum/sumsq; next layer derives scale/shift on the fly.
// ---------------------------------------------------------------------------

// workspace layout (float element offsets)
//   dynk   [0, 1071104)        k1(6144) k2(131072) k3(147456) k4(524288) k5(262144)
//   stats  [1071104, 1073024)  st1(128) st2(256) st3(512) st4(1024)
//   t5     [1073024, 4284288)  fp32 (128,49,512)
// byte offsets after that:
//   yA @ 17137152 : bf16, 33554432 elems (y1, y3)
//   yB @ 84246016 : bf16, 16777216 elems (y2, y4)
// total ~118 MB

__global__ __launch_bounds__(256) void prep_kernel(
    const int* __restrict__ label, const float* __restrict__ emb,
    const float* __restrict__ l1w, const float* __restrict__ l1b,
    const float* __restrict__ l2w, const float* __restrict__ l2b,
    const float* __restrict__ l3w, const float* __restrict__ l3b,
    const float* __restrict__ l4w, const float* __restrict__ l4b,
    const float* __restrict__ l5w, const float* __restrict__ l5b,
    float* __restrict__ dynk, float* __restrict__ stats,
    float* __restrict__ labelOut)
{
    const int tid = threadIdx.x;
    if (blockIdx.x == gridDim.x - 1) {                   // housekeeping block
        for (int i = tid; i < 1920; i += 256) stats[i] = 0.0f;
        if (tid < 128) labelOut[tid] = (float)label[tid];
        return;
    }
    int idx = blockIdx.x * 256 + tid;
    if (idx >= 1071104) return;
    const float* w; const float* bb; int loc, ckk;
    if (idx < 6144)        { w = l1w; bb = l1b; loc = idx;          ckk = 48;   }
    else if (idx < 137216) { w = l2w; bb = l2b; loc = idx - 6144;   ckk = 1024; }
    else if (idx < 284672) { w = l3w; bb = l3b; loc = idx - 137216; ckk = 1152; }
    else if (idx < 808960) { w = l4w; bb = l4b; loc = idx - 284672; ckk = 4096; }
    else                   { w = l5w; bb = l5b; loc = idx - 808960; ckk = 2048; }
    int b   = loc / ckk;
    int col = loc - b * ckk;
    int lab = label[b];
    float acc = bb[col];
    #pragma unroll
    for (int m = 0; m < 5; ++m)
        acc = fmaf(emb[lab * 5 + m], w[m * ckk + col], acc);
    dynk[idx] = tanhf(acc);
}

// ---------------------------------------------------------------------------
// Fused layer: dwconv (stride 2, pad 1) + mix + lrelu + stats.
// Block = 256 threads, covers one tile of TP x TP output positions (one b).
// Thread grid for mix: 16 (ty, pos) x 16 (td, d); thread tile TPP x 4.
// ---------------------------------------------------------------------------
template<int CIN, int COUT, int KS, int HIN, int HOUT, int TP, bool FIRST>
__global__ __launch_bounds__(256) void fused_layer(
    const void* __restrict__ xv,
    const float* __restrict__ statsPrev,
    const float* __restrict__ gPrev, const float* __restrict__ bPrev,
    const float* __restrict__ dynk,
    const float* __restrict__ W, const float* __restrict__ bias,
    bf16* __restrict__ y, float* __restrict__ statsOut,
    int totalTiles)
{
    constexpr int NPOS   = TP * TP;
    constexpr int TPP    = NPOS / 16;          // pos per thread (4 or 1)
    constexpr int DWS    = NPOS + 4;           // padded stride, 16B-aligned rows
    constexpr int KCH    = (CIN < 64) ? CIN : 64;
    constexpr int TILESX = HOUT / TP;
    constexpr int TPS    = TILESX * TILESX;
    constexpr int KSK    = KS * KS;
    constexpr int INP    = FIRST ? (TP * 2 + 2) : 1;   // input patch side (L1)
    const float NPREV_INV = 1.0f / (128.0f * (float)HIN * (float)HIN);

    __shared__ float dwT[CIN * DWS];           // transposed dw result [c][pos]
    __shared__ float Blds[KCH * 64];           // W tile [kk][d]
    __shared__ float klds[KSK * CIN];          // dyn kernel [tap][c]
    __shared__ float scaleL[CIN];
    __shared__ float shiftL[CIN];
    __shared__ float sumL[COUT];
    __shared__ float sqL[COUT];
    __shared__ float patch[FIRST ? 3 * INP * INP : 1];

    const float* xf = (const float*)xv;
    const bf16*  xb = (const bf16*)xv;

    const int tid = threadIdx.x;
    const int td  = tid & 15;
    const int ty  = tid >> 4;

    if constexpr (!FIRST) {                    // derive prev-layer BN affine
        for (int c = tid; c < CIN; c += 256) {
            float s = statsPrev[c];
            float q = statsPrev[CIN + c];
            float m = s * NPREV_INV;
            float var = fmaf(q, NPREV_INV, -m * m);
            float inv = rsqrtf(var + 1e-5f);
            float sc = gPrev[c] * inv;
            scaleL[c] = sc;
            shiftL[c] = fmaf(-m, sc, bPrev[c]);
        }
    }
    for (int d = tid; d < COUT; d += 256) { sumL[d] = 0.f; sqL[d] = 0.f; }

    for (int tile = blockIdx.x; tile < totalTiles; tile += gridDim.x) {
        const int b    = tile / TPS;
        const int tloc = tile - b * TPS;
        const int tY   = tloc / TILESX;
        const int tX   = tloc - tY * TILESX;
        const int oy0  = tY * TP, ox0 = tX * TP;

        __syncthreads();   // protect dwT/klds from previous iteration's readers
        {   // stage dyn kernel, transposed -> klds[tap][c]
            const float* kp = dynk + (long)b * (CIN * KSK);
            for (int i = tid; i < CIN * KSK; i += 256) {
                int c = i / KSK, t = i - c * KSK;
                klds[t * CIN + c] = kp[i];
            }
        }
        if constexpr (FIRST) {   // stage padded NCHW input patch
            const int iy0 = oy0 * 2 - 1, ix0 = ox0 * 2 - 1;
            for (int i = tid; i < 3 * INP * INP; i += 256) {
                int c  = i / (INP * INP);
                int r  = i - c * INP * INP;
                int py = r / INP, px = r - py * INP;
                int gy = iy0 + py, gx = ix0 + px;
                float v = 0.f;
                if (gy >= 0 && gy < HIN && gx >= 0 && gx < HIN)
                    v = xf[((long)b * 3 + c) * (HIN * HIN) + gy * HIN + gx];
                patch[i] = v;
            }
        }
        __syncthreads();

        // ---- phase 1: depthwise conv -> dwT[c][pos] ----
        for (int i = tid; i < NPOS * CIN; i += 256) {
            int c = i % CIN, p = i / CIN;      // c fastest -> coalesced x reads
            int py = p / TP, px = p - py * TP;
            float acc = 0.f;
            if constexpr (FIRST) {
                #pragma unroll
                for (int kh = 0; kh < KS; ++kh)
                    #pragma unroll
                    for (int kw = 0; kw < KS; ++kw) {
                        float pv = patch[c * INP * INP + (py * 2 + kh) * INP + (px * 2 + kw)];
                        acc = fmaf(pv, klds[(kh * KS + kw) * CIN + c], acc);
                    }
            } else {
                int oy = oy0 + py, ox = ox0 + px;
                float sc = scaleL[c], sh = shiftL[c];
                #pragma unroll
                for (int kh = 0; kh < KS; ++kh) {
                    int hy = oy * 2 - 1 + kh;
                    #pragma unroll
                    for (int kw = 0; kw < KS; ++kw) {
                        int hx = ox * 2 - 1 + kw;
                        if (hy >= 0 && hy < HIN && hx >= 0 && hx < HIN) {
                            float xvv = __bfloat162float(xb[(((long)b * HIN + hy) * HIN + hx) * CIN + c]);
                            acc = fmaf(fmaf(xvv, sc, sh), klds[(kh * KS + kw) * CIN + c], acc);
                        }
                    }
                }
            }
            dwT[c * DWS + p] = acc;
        }

        // ---- phase 2: mix GEMM (NPOS x COUT, K=CIN) + epilogue ----
        for (int dBase = 0; dBase < COUT; dBase += 64) {
            float acc[TPP][4];
            #pragma unroll
            for (int ii = 0; ii < TPP; ++ii)
                #pragma unroll
                for (int j = 0; j < 4; ++j) acc[ii][j] = 0.f;

            for (int kb = 0; kb < CIN; kb += KCH) {
                __syncthreads();
                for (int i = tid; i < KCH * 64; i += 256) {
                    int kk = i >> 6, d = i & 63;
                    Blds[i] = W[(long)(kb + kk) * COUT + dBase + d];
                }
                __syncthreads();
                #pragma unroll 4
                for (int kk = 0; kk < KCH; ++kk) {
                    const float4 b4 = *(const float4*)&Blds[kk * 64 + td * 4];
                    if constexpr (TPP == 4) {
                        const float4 a4 = *(const float4*)&dwT[(kb + kk) * DWS + ty * 4];
                        const float av[4] = {a4.x, a4.y, a4.z, a4.w};
                        #pragma unroll
                        for (int ii = 0; ii < 4; ++ii) {
                            acc[ii][0] = fmaf(av[ii], b4.x, acc[ii][0]);
                            acc[ii][1] = fmaf(av[ii], b4.y, acc[ii][1]);
                            acc[ii][2] = fmaf(av[ii], b4.z, acc[ii][2]);
                            acc[ii][3] = fmaf(av[ii], b4.w, acc[ii][3]);
                        }
                    } else {
                        const float a = dwT[(kb + kk) * DWS + ty];
                        acc[0][0] = fmaf(a, b4.x, acc[0][0]);
                        acc[0][1] = fmaf(a, b4.y, acc[0][1]);
                        acc[0][2] = fmaf(a, b4.z, acc[0][2]);
                        acc[0][3] = fmaf(a, b4.w, acc[0][3]);
                    }
                }
            }
            // epilogue: bias + lrelu + stats + bf16 store
            const float4 bi = *(const float4*)&bias[dBase + td * 4];
            float sreg[4] = {0.f, 0.f, 0.f, 0.f};
            float qreg[4] = {0.f, 0.f, 0.f, 0.f};
            #pragma unroll
            for (int ii = 0; ii < TPP; ++ii) {
                const int p  = ty * TPP + ii;
                const int py = p / TP, px = p - py * TP;
                const long row = ((long)b * HOUT + (oy0 + py)) * HOUT + (ox0 + px);
                float v[4];
                v[0] = acc[ii][0] + bi.x;
                v[1] = acc[ii][1] + bi.y;
                v[2] = acc[ii][2] + bi.z;
                v[3] = acc[ii][3] + bi.w;
                union { ushort4 u; bf16 h[4]; } pk;
                #pragma unroll
                for (int j = 0; j < 4; ++j) {
                    float vv = v[j];
                    vv = vv > 0.f ? vv : 0.2f * vv;     // leaky relu 0.2
                    sreg[j] += vv;
                    qreg[j] = fmaf(vv, vv, qreg[j]);
                    pk.h[j] = __float2bfloat16(vv);
                }
                *(ushort4*)&y[row * COUT + dBase + td * 4] = pk.u;
            }
            #pragma unroll
            for (int j = 0; j < 4; ++j) {
                atomicAdd(&sumL[dBase + td * 4 + j], sreg[j]);
                atomicAdd(&sqL [dBase + td * 4 + j], qreg[j]);
            }
        }
    }
    __syncthreads();
    for (int d = tid; d < COUT; d += 256) {
        atomicAdd(&statsOut[d],        sumL[d]);
        atomicAdd(&statsOut[COUT + d], sqL[d]);
    }
}

// ---------------------------------------------------------------------------
// Layer 5 depthwise conv: k=2, stride 1, pad 0, 8x8 -> 7x7, applies BN4.
// ---------------------------------------------------------------------------
__global__ __launch_bounds__(256) void dwconv5_kernel(
    const bf16* __restrict__ y4, const float* __restrict__ st4,
    const float* __restrict__ g4, const float* __restrict__ b4,
    const float* __restrict__ k5, float* __restrict__ t5)
{
    int idx = blockIdx.x * 256 + threadIdx.x;   // exactly 12544*256 = 3211264
    int c   = idx & 511;
    int r   = idx >> 9;
    int b   = r / 49;
    int pos = r - b * 49;
    int py  = pos / 7, px = pos - py * 7;
    const float NINV = 1.0f / 8192.0f;          // B*8*8
    float s = st4[c], q = st4[512 + c];
    float m = s * NINV;
    float var = fmaf(q, NINV, -m * m);
    float inv = rsqrtf(var + 1e-5f);
    float sc = g4[c] * inv;
    float sh = fmaf(-m, sc, b4[c]);
    const float* kp = k5 + ((long)b * 512 + c) * 4;
    float acc = 0.f;
    #pragma unroll
    for (int kh = 0; kh < 2; ++kh)
        #pragma unroll
        for (int kw = 0; kw < 2; ++kw) {
            float xv = __bfloat162float(y4[(((long)b * 8 + py + kh) * 8 + px + kw) * 512 + c]);
            acc = fmaf(fmaf(xv, sc, sh), kp[kh * 2 + kw], acc);
        }
    t5[idx] = acc;
}

// ---------------------------------------------------------------------------
// Layer 5 mix: GEMM M=6272(=98*64) K=512 N=512 + sigmoid, NCHW output
// via LDS transpose for coalesced stores.
// ---------------------------------------------------------------------------
__global__ __launch_bounds__(256) void mix5_kernel(
    const float* __restrict__ t5, const float* __restrict__ W,
    const float* __restrict__ bias, float* __restrict__ out)
{
    __shared__ float AT[64 * 68];   // A^T [k][m], padded
    __shared__ float Bl[64 * 64];   // B   [k][d]
    const int tid = threadIdx.x;
    const int td  = tid & 15, ty = tid >> 4;
    const int mT  = blockIdx.x % 98;
    const int nT  = blockIdx.x / 98;
    const int m0  = mT * 64, n0 = nT * 64;
    float acc[4][4] = {};
    for (int kb = 0; kb < 512; kb += 64) {
        __syncthreads();
        for (int i = tid; i < 4096; i += 256) {
            int klo = i & 63, hi = i >> 6;
            AT[klo * 68 + hi] = t5[(long)(m0 + hi) * 512 + kb + klo];   // hi = m
            Bl[hi * 64 + klo] = W [(long)(kb + hi) * 512 + n0 + klo];   // hi = k, klo = d
        }
        __syncthreads();
        #pragma unroll 8
        for (int kk = 0; kk < 64; ++kk) {
            const float4 a4 = *(const float4*)&AT[kk * 68 + ty * 4];
            const float4 b4 = *(const float4*)&Bl[kk * 64 + td * 4];
            const float av[4] = {a4.x, a4.y, a4.z, a4.w};
            #pragma unroll
            for (int ii = 0; ii < 4; ++ii) {
                acc[ii][0] = fmaf(av[ii], b4.x, acc[ii][0]);
                acc[ii][1] = fmaf(av[ii], b4.y, acc[ii][1]);
                acc[ii][2] = fmaf(av[ii], b4.z, acc[ii][2]);
                acc[ii][3] = fmaf(av[ii], b4.w, acc[ii][3]);
            }
        }
    }
    __syncthreads();
    float* C = AT;   // reuse, stride 68: C[m][d]
    const float4 bi = *(const float4*)&bias[n0 + td * 4];
    const float bv[4] = {bi.x, bi.y, bi.z, bi.w};
    #pragma unroll
    for (int ii = 0; ii < 4; ++ii) {
        float4 v;
        v.x = 1.f / (1.f + __expf(-(acc[ii][0] + bv[0])));
        v.y = 1.f / (1.f + __expf(-(acc[ii][1] + bv[1])));
        v.z = 1.f / (1.f + __expf(-(acc[ii][2] + bv[2])));
        v.w = 1.f / (1.f + __expf(-(acc[ii][3] + bv[3])));
        *(float4*)&C[(ty * 4 + ii) * 68 + td * 4] = v;
    }
    __syncthreads();
    for (int i = tid; i < 4096; i += 256) {
        int mm = i & 63, d = i >> 6;
        float v = C[mm * 68 + d];
        int m = m0 + mm;
        int b = m / 49, pos = m - b * 49;
        out[((long)b * 512 + n0 + d) * 49 + pos] = v;   // ~coalesced over pos
    }
}

// ---------------------------------------------------------------------------

extern "C" void kernel_launch(void* const* d_in, const int* in_sizes, int n_in,
                              void* d_out, int out_size, void* d_ws, size_t ws_size,
                              hipStream_t stream)
{
    const float* input = (const float*)d_in[0];
    const int*   label = (const int*)d_in[1];
    const float* emb   = (const float*)d_in[2];
    const float* lw[5] = {(const float*)d_in[3], (const float*)d_in[5], (const float*)d_in[7],
                          (const float*)d_in[9], (const float*)d_in[11]};
    const float* lb[5] = {(const float*)d_in[4], (const float*)d_in[6], (const float*)d_in[8],
                          (const float*)d_in[10], (const float*)d_in[12]};
    const float* cmw[5] = {(const float*)d_in[13], (const float*)d_in[15], (const float*)d_in[17],
                           (const float*)d_in[19], (const float*)d_in[21]};
    const float* cmb[5] = {(const float*)d_in[14], (const float*)d_in[16], (const float*)d_in[18],
                           (const float*)d_in[20], (const float*)d_in[22]};
    const float* bng[4] = {(const float*)d_in[23], (const float*)d_in[25],
                           (const float*)d_in[27], (const float*)d_in[29]};
    const float* bnb[4] = {(const float*)d_in[24], (const float*)d_in[26],
                           (const float*)d_in[28], (const float*)d_in[30]};
    float* out = (float*)d_out;

    float* wsf   = (float*)d_ws;
    float* dynk  = wsf;
    float* stats = wsf + 1071104;
    float* t5    = wsf + 1073024;
    bf16*  yA    = (bf16*)((char*)d_ws + 17137152);   // 33554432 bf16
    bf16*  yB    = (bf16*)((char*)d_ws + 84246016);   // 16777216 bf16

    const float* k1 = dynk;
    const float* k2 = dynk + 6144;
    const float* k3 = dynk + 137216;
    const float* k4 = dynk + 284672;
    const float* k5 = dynk + 808960;
    float* st1 = stats;
    float* st2 = stats + 128;
    float* st3 = stats + 384;
    float* st4 = stats + 896;

    prep_kernel<<<4186, 256, 0, stream>>>(label, emb,
        lw[0], lb[0], lw[1], lb[1], lw[2], lb[2], lw[3], lb[3], lw[4], lb[4],
        dynk, stats, out + 3211264);

    // <CIN, COUT, KS, HIN, HOUT, TP, FIRST>
    fused_layer<3,   64, 4, 128, 64, 8, true ><<<2048, 256, 0, stream>>>(
        input, nullptr, nullptr, nullptr, k1, cmw[0], cmb[0], yA, st1, 8192);
    fused_layer<64, 128, 4,  64, 32, 8, false><<<2048, 256, 0, stream>>>(
        yA, st1, bng[0], bnb[0], k2, cmw[1], cmb[1], yB, st2, 2048);
    fused_layer<128,256, 3,  32, 16, 8, false><<<512, 256, 0, stream>>>(
        yB, st2, bng[1], bnb[1], k3, cmw[2], cmb[2], yA, st3, 512);
    fused_layer<256,512, 4,  16,  8, 4, false><<<512, 256, 0, stream>>>(
        yA, st3, bng[2], bnb[2], k4, cmw[3], cmb[3], yB, st4, 512);

    dwconv5_kernel<<<12544, 256, 0, stream>>>(yB, st4, bng[3], bnb[3], k5, t5);
    mix5_kernel<<<784, 256, 0, stream>>>(t5, cmw[4], cmb[4], out);
}

// Round 2
// 720.208 us; speedup vs baseline: 1.2289x; 1.2289x over previous
//
#include <hip/hip_runtime.h>
#include <hip/hip_bf16.h>

typedef __hip_bfloat16 bf16;
using short8  = __attribute__((ext_vector_type(8))) short;
using floatx4 = __attribute__((ext_vector_type(4))) float;

__device__ __forceinline__ float b2f(unsigned short u) {
    union { unsigned int i; float f; } v; v.i = ((unsigned int)u) << 16; return v.f;
}
__device__ __forceinline__ unsigned short f2b(float f) {
    bf16 h = __float2bfloat16(f);
    return *(unsigned short*)&h;
}

// ---------------------------------------------------------------------------
// Workspace layout (bytes):
//   dynk  @ 0          : 1071104 fp32  (k1 6144 | k2 131072 | k3 147456 | k4 524288 | k5 262144)
//   stats @ 4284416    : 1920 fp32     (st1 128 | st2 256 | st3 512 | st4 1024)
//   WT    @ 4292096    : 434176 bf16   (wt2 8192 | wt3 32768 | wt4 131072 | wt5 262144)
//   S1    @ 5242880    : 67.1 MB bf16  (y1, then y2, y3, y4)
//   S2    @ 72351744   : 16.8 MB bf16  (A2, then A3, A4, A5)
// total ~89 MB
// ---------------------------------------------------------------------------

__global__ __launch_bounds__(256) void prep_kernel(
    const int* __restrict__ label, const float* __restrict__ emb,
    const float* __restrict__ l1w, const float* __restrict__ l1b,
    const float* __restrict__ l2w, const float* __restrict__ l2b,
    const float* __restrict__ l3w, const float* __restrict__ l3b,
    const float* __restrict__ l4w, const float* __restrict__ l4b,
    const float* __restrict__ l5w, const float* __restrict__ l5b,
    float* __restrict__ dynk, float* __restrict__ stats,
    float* __restrict__ labelOut)
{
    const int tid = threadIdx.x;
    if (blockIdx.x == gridDim.x - 1) {                   // housekeeping block
        for (int i = tid; i < 1920; i += 256) stats[i] = 0.0f;
        if (tid < 128) labelOut[tid] = (float)label[tid];
        return;
    }
    int idx = blockIdx.x * 256 + tid;
    if (idx >= 1071104) return;
    const float* w; const float* bb; int loc, ckk;
    if (idx < 6144)        { w = l1w; bb = l1b; loc = idx;          ckk = 48;   }
    else if (idx < 137216) { w = l2w; bb = l2b; loc = idx - 6144;   ckk = 1024; }
    else if (idx < 284672) { w = l3w; bb = l3b; loc = idx - 137216; ckk = 1152; }
    else if (idx < 808960) { w = l4w; bb = l4b; loc = idx - 284672; ckk = 4096; }
    else                   { w = l5w; bb = l5b; loc = idx - 808960; ckk = 2048; }
    int b   = loc / ckk;
    int col = loc - b * ckk;
    int lab = label[b];
    float acc = bb[col];
    #pragma unroll
    for (int m = 0; m < 5; ++m)
        acc = fmaf(emb[lab * 5 + m], w[m * ckk + col], acc);
    dynk[idx] = tanhf(acc);
}

// transpose-convert channel-mix weights: WT[n][k] = bf16(W[k][n]), layers 2..5
__global__ __launch_bounds__(256) void wt_kernel(
    const float* __restrict__ w2, const float* __restrict__ w3,
    const float* __restrict__ w4, const float* __restrict__ w5,
    bf16* __restrict__ wt2, bf16* __restrict__ wt3,
    bf16* __restrict__ wt4, bf16* __restrict__ wt5)
{
    __shared__ float T[32][33];
    const int tid = threadIdx.x;
    int t = blockIdx.x;
    const float* W; bf16* WT; int K, N, tl;
    if (t < 8)        { W = w2; WT = wt2; K = 64;  N = 128; tl = t; }
    else if (t < 40)  { W = w3; WT = wt3; K = 128; N = 256; tl = t - 8; }
    else if (t < 168) { W = w4; WT = wt4; K = 256; N = 512; tl = t - 40; }
    else              { W = w5; WT = wt5; K = 512; N = 512; tl = t - 168; }
    const int NT = N >> 5;
    const int kt = tl / NT, nt = tl - kt * NT;
    const int k0 = kt * 32, n0 = nt * 32;
    const int cc = tid & 31, rr = tid >> 5;
    #pragma unroll
    for (int it = 0; it < 4; ++it) {
        int k = rr + it * 8;
        T[k][cc] = W[(long)(k0 + k) * N + n0 + cc];
    }
    __syncthreads();
    #pragma unroll
    for (int it = 0; it < 4; ++it) {
        int n = rr + it * 8;
        WT[(long)(n0 + n) * K + k0 + cc] = __float2bfloat16(T[cc][n]);
    }
}

// ---------------------------------------------------------------------------
// Layer 1 (K=3, not MFMA-shaped): fused dwconv + mix + lrelu + stats (verified)
// ---------------------------------------------------------------------------
template<int CIN, int COUT, int KS, int HIN, int HOUT, int TP>
__global__ __launch_bounds__(256) void fused_l1(
    const float* __restrict__ xf,
    const float* __restrict__ dynk,
    const float* __restrict__ W, const float* __restrict__ bias,
    bf16* __restrict__ y, float* __restrict__ statsOut,
    int totalTiles)
{
    constexpr int NPOS   = TP * TP;
    constexpr int TPP    = NPOS / 16;
    constexpr int DWS    = NPOS + 4;
    constexpr int TILESX = HOUT / TP;
    constexpr int TPS    = TILESX * TILESX;
    constexpr int KSK    = KS * KS;
    constexpr int INP    = TP * 2 + 2;

    __shared__ float dwT[CIN * DWS];
    __shared__ float Blds[CIN * 64];
    __shared__ float klds[KSK * CIN];
    __shared__ float sumL[COUT];
    __shared__ float sqL[COUT];
    __shared__ float patch[CIN * INP * INP];

    const int tid = threadIdx.x;
    const int td  = tid & 15;
    const int ty  = tid >> 4;

    for (int d = tid; d < COUT; d += 256) { sumL[d] = 0.f; sqL[d] = 0.f; }

    for (int tile = blockIdx.x; tile < totalTiles; tile += gridDim.x) {
        const int b    = tile / TPS;
        const int tloc = tile - b * TPS;
        const int tY   = tloc / TILESX;
        const int tX   = tloc - tY * TILESX;
        const int oy0  = tY * TP, ox0 = tX * TP;

        __syncthreads();
        {
            const float* kp = dynk + (long)b * (CIN * KSK);
            for (int i = tid; i < CIN * KSK; i += 256) {
                int c = i / KSK, t = i - c * KSK;
                klds[t * CIN + c] = kp[i];
            }
        }
        {
            const int iy0 = oy0 * 2 - 1, ix0 = ox0 * 2 - 1;
            for (int i = tid; i < CIN * INP * INP; i += 256) {
                int c  = i / (INP * INP);
                int r  = i - c * INP * INP;
                int py = r / INP, px = r - py * INP;
                int gy = iy0 + py, gx = ix0 + px;
                float v = 0.f;
                if (gy >= 0 && gy < HIN && gx >= 0 && gx < HIN)
                    v = xf[((long)b * CIN + c) * (HIN * HIN) + gy * HIN + gx];
                patch[i] = v;
            }
        }
        __syncthreads();

        for (int i = tid; i < NPOS * CIN; i += 256) {
            int c = i % CIN, p = i / CIN;
            int py = p / TP, px = p - py * TP;
            float acc = 0.f;
            #pragma unroll
            for (int kh = 0; kh < KS; ++kh)
                #pragma unroll
                for (int kw = 0; kw < KS; ++kw) {
                    float pv = patch[c * INP * INP + (py * 2 + kh) * INP + (px * 2 + kw)];
                    acc = fmaf(pv, klds[(kh * KS + kw) * CIN + c], acc);
                }
            dwT[c * DWS + p] = acc;
        }

        for (int dBase = 0; dBase < COUT; dBase += 64) {
            float acc[TPP][4];
            #pragma unroll
            for (int ii = 0; ii < TPP; ++ii)
                #pragma unroll
                for (int j = 0; j < 4; ++j) acc[ii][j] = 0.f;

            __syncthreads();
            for (int i = tid; i < CIN * 64; i += 256) {
                int kk = i >> 6, d = i & 63;
                Blds[i] = W[(long)kk * COUT + dBase + d];
            }
            __syncthreads();
            #pragma unroll
            for (int kk = 0; kk < CIN; ++kk) {
                const float4 b4 = *(const float4*)&Blds[kk * 64 + td * 4];
                const float4 a4 = *(const float4*)&dwT[kk * DWS + ty * 4];
                const float av[4] = {a4.x, a4.y, a4.z, a4.w};
                #pragma unroll
                for (int ii = 0; ii < 4; ++ii) {
                    acc[ii][0] = fmaf(av[ii], b4.x, acc[ii][0]);
                    acc[ii][1] = fmaf(av[ii], b4.y, acc[ii][1]);
                    acc[ii][2] = fmaf(av[ii], b4.z, acc[ii][2]);
                    acc[ii][3] = fmaf(av[ii], b4.w, acc[ii][3]);
                }
            }
            const float4 bi = *(const float4*)&bias[dBase + td * 4];
            float sreg[4] = {0.f, 0.f, 0.f, 0.f};
            float qreg[4] = {0.f, 0.f, 0.f, 0.f};
            #pragma unroll
            for (int ii = 0; ii < TPP; ++ii) {
                const int p  = ty * TPP + ii;
                const int py = p / TP, px = p - py * TP;
                const long row = ((long)b * HOUT + (oy0 + py)) * HOUT + (ox0 + px);
                float v[4];
                v[0] = acc[ii][0] + bi.x;
                v[1] = acc[ii][1] + bi.y;
                v[2] = acc[ii][2] + bi.z;
                v[3] = acc[ii][3] + bi.w;
                union { ushort4 u; bf16 h[4]; } pk;
                #pragma unroll
                for (int j = 0; j < 4; ++j) {
                    float vv = v[j];
                    vv = vv > 0.f ? vv : 0.2f * vv;
                    sreg[j] += vv;
                    qreg[j] = fmaf(vv, vv, qreg[j]);
                    pk.h[j] = __float2bfloat16(vv);
                }
                *(ushort4*)&y[row * COUT + dBase + td * 4] = pk.u;
            }
            #pragma unroll
            for (int j = 0; j < 4; ++j) {
                atomicAdd(&sumL[dBase + td * 4 + j], sreg[j]);
                atomicAdd(&sqL [dBase + td * 4 + j], qreg[j]);
            }
        }
    }
    __syncthreads();
    for (int d = tid; d < COUT; d += 256) {
        atomicAdd(&statsOut[d],        sumL[d]);
        atomicAdd(&statsOut[COUT + d], sqL[d]);
    }
}

// ---------------------------------------------------------------------------
// Depthwise conv (layers 2..5): reads bf16 NHWC y_prev, folds prev-layer BN,
// writes bf16 NHWC A. One thread per (b,oy,ox, channel-pair).
// ---------------------------------------------------------------------------
template<int C, int KS, int HIN, int HOUT, int STRIDE, int PAD>
__global__ __launch_bounds__(256) void dw_kernel(
    const bf16* __restrict__ x, const float* __restrict__ st,
    const float* __restrict__ g, const float* __restrict__ bb,
    const float* __restrict__ dynk, bf16* __restrict__ outA, float NINV)
{
    const int idx = blockIdx.x * 256 + threadIdx.x;
    constexpr int CH = C / 2;
    const int cp  = idx % CH;
    const int r   = idx / CH;
    const int c   = cp * 2;
    const int b   = r / (HOUT * HOUT);
    const int pos = r % (HOUT * HOUT);
    const int oy  = pos / HOUT, ox = pos % HOUT;

    float2 sv = *(const float2*)&st[c];
    float2 qv = *(const float2*)&st[C + c];
    float2 gv = *(const float2*)&g[c];
    float2 bv = *(const float2*)&bb[c];
    float mm0 = sv.x * NINV, mm1 = sv.y * NINV;
    float v0 = fmaf(qv.x, NINV, -mm0 * mm0);
    float v1 = fmaf(qv.y, NINV, -mm1 * mm1);
    float sc0 = gv.x * rsqrtf(v0 + 1e-5f);
    float sc1 = gv.y * rsqrtf(v1 + 1e-5f);
    float sh0 = fmaf(-mm0, sc0, bv.x);
    float sh1 = fmaf(-mm1, sc1, bv.y);

    const float* kp = dynk + ((long)b * C + c) * (KS * KS);
    float acc0 = 0.f, acc1 = 0.f;
    #pragma unroll
    for (int kh = 0; kh < KS; ++kh) {
        int iy = oy * STRIDE - PAD + kh;
        if (iy < 0 || iy >= HIN) continue;
        #pragma unroll
        for (int kw = 0; kw < KS; ++kw) {
            int ix = ox * STRIDE - PAD + kw;
            if (ix < 0 || ix >= HIN) continue;
            ushort2 u = *(const ushort2*)&x[((long)(b * HIN + iy) * HIN + ix) * C + c];
            float x0 = fmaf(b2f(u.x), sc0, sh0);
            float x1 = fmaf(b2f(u.y), sc1, sh1);
            acc0 = fmaf(x0, kp[kh * KS + kw], acc0);
            acc1 = fmaf(x1, kp[KS * KS + kh * KS + kw], acc1);
        }
    }
    ushort2 o; o.x = f2b(acc0); o.y = f2b(acc1);
    *(ushort2*)&outA[(long)r * C + c] = o;
}

// ---------------------------------------------------------------------------
// MFMA bf16 GEMM: C[M,COUT] = A[M,K] x W[K,COUT], 128x128 block tile.
// A NHWC bf16 (K contiguous); WT[n][k] bf16 (pre-transposed). Epilogue:
// bias + lrelu + bf16 NHWC store + per-channel stats (or sigmoid + NCHW fp32).
// Fragments: A[m=lane&15][k=quad*8+j], B from W^T rows, D col=lane&15,
// row=quad*4+reg (gfx950-verified layouts).
// ---------------------------------------------------------------------------
template<int K, int COUT, bool LAST>
__global__ __launch_bounds__(256) void gemm_layer(
    const bf16* __restrict__ A, const bf16* __restrict__ WT,
    const float* __restrict__ bias, bf16* __restrict__ y,
    float* __restrict__ statsOut, float* __restrict__ outF, int Mtiles)
{
    constexpr int SK = 40;    // LDS row stride (bf16) for 128x32 tiles, padded
    constexpr int CS = 136;   // LDS row stride (bf16) for 128x128 C tile
    __shared__ __align__(16) unsigned short smem[17408];   // 34816 B, reused
    unsigned short* As  = smem;            // [128][SK]
    unsigned short* Bs  = smem + 5120;     // [128][SK]
    unsigned short* Csh = smem;            // [128][CS]
    __shared__ float sums[128], sqs[128];

    const int tid  = threadIdx.x;
    const int lane = tid & 63;
    const int w    = tid >> 6;
    const int wm   = (w >> 1) * 64, wn = (w & 1) * 64;
    const int lm   = lane & 15, lq = lane >> 4;
    const int mt   = blockIdx.x % Mtiles;
    const int nt   = blockIdx.x / Mtiles;
    const long m0  = (long)mt * 128;
    const int  n0  = nt * 128;

    floatx4 acc[4][4];
    #pragma unroll
    for (int i = 0; i < 4; ++i)
        #pragma unroll
        for (int j = 0; j < 4; ++j) acc[i][j] = (floatx4)0.0f;

    for (int kb = 0; kb < K; kb += 32) {
        __syncthreads();
        #pragma unroll
        for (int s = 0; s < 2; ++s) {
            int i = tid + s * 256;          // 512 16-B granules each for A and B
            int m = i >> 2, q = i & 3;
            uint4 va = *(const uint4*)(A  + ((m0 + m) * K + kb + q * 8));
            uint4 vb = *(const uint4*)(WT + ((long)(n0 + m) * K + kb + q * 8));
            *(uint4*)&As[m * SK + q * 8] = va;
            *(uint4*)&Bs[m * SK + q * 8] = vb;
        }
        __syncthreads();
        short8 af[4], bfr[4];
        #pragma unroll
        for (int i = 0; i < 4; ++i) {
            af[i]  = *(const short8*)&As[(wm + i * 16 + lm) * SK + lq * 8];
            bfr[i] = *(const short8*)&Bs[(wn + i * 16 + lm) * SK + lq * 8];
        }
        #pragma unroll
        for (int i = 0; i < 4; ++i)
            #pragma unroll
            for (int j = 0; j < 4; ++j)
                acc[i][j] = __builtin_amdgcn_mfma_f32_16x16x32_bf16(af[i], bfr[j], acc[i][j], 0, 0, 0);
    }
    __syncthreads();

    float bj[4];
    #pragma unroll
    for (int j = 0; j < 4; ++j) bj[j] = bias[n0 + wn + j * 16 + lm];

    if constexpr (!LAST) {
        if (tid < 128) { sums[tid] = 0.f; sqs[tid] = 0.f; }
        #pragma unroll
        for (int i = 0; i < 4; ++i)
            #pragma unroll
            for (int j = 0; j < 4; ++j) {
                int c = wn + j * 16 + lm;
                #pragma unroll
                for (int rg = 0; rg < 4; ++rg) {
                    int r = wm + i * 16 + lq * 4 + rg;
                    float v = acc[i][j][rg] + bj[j];
                    v = v > 0.f ? v : 0.2f * v;
                    Csh[r * CS + c] = f2b(v);
                }
            }
        __syncthreads();
        const int cg = tid & 15, mr = tid >> 4;
        float sacc[8], qacc[8];
        #pragma unroll
        for (int t = 0; t < 8; ++t) { sacc[t] = 0.f; qacc[t] = 0.f; }
        #pragma unroll
        for (int it = 0; it < 8; ++it) {
            int m = mr + it * 16;
            uint4 pk = *(const uint4*)&Csh[m * CS + cg * 8];
            *(uint4*)&y[(m0 + m) * COUT + n0 + cg * 8] = pk;
            const unsigned short* pu = (const unsigned short*)&pk;
            #pragma unroll
            for (int t = 0; t < 8; ++t) {
                float f = b2f(pu[t]);
                sacc[t] += f;
                qacc[t] = fmaf(f, f, qacc[t]);
            }
        }
        #pragma unroll
        for (int t = 0; t < 8; ++t) {
            atomicAdd(&sums[cg * 8 + t], sacc[t]);
            atomicAdd(&sqs [cg * 8 + t], qacc[t]);
        }
        __syncthreads();
        if (tid < 128) {
            atomicAdd(&statsOut[n0 + tid],        sums[tid]);
            atomicAdd(&statsOut[COUT + n0 + tid], sqs[tid]);
        }
    } else {
        // transposed C tile: Csh[c][r] holds pre-sigmoid value
        #pragma unroll
        for (int i = 0; i < 4; ++i)
            #pragma unroll
            for (int j = 0; j < 4; ++j) {
                int c  = wn + j * 16 + lm;
                int rb = wm + i * 16 + lq * 4;
                ushort4 pk;
                unsigned short* pp = (unsigned short*)&pk;
                #pragma unroll
                for (int rg = 0; rg < 4; ++rg)
                    pp[rg] = f2b(acc[i][j][rg] + bj[j]);
                *(ushort4*)&Csh[c * CS + rb] = pk;
            }
        __syncthreads();
        const int mg = tid & 15, nr = tid >> 4;
        #pragma unroll
        for (int it = 0; it < 8; ++it) {
            int n = nr + it * 16;
            uint4 pk = *(const uint4*)&Csh[n * CS + mg * 8];
            const unsigned short* pu = (const unsigned short*)&pk;
            #pragma unroll
            for (int t = 0; t < 8; ++t) {
                int m = (int)m0 + mg * 8 + t;
                int b = m / 49, pos = m - b * 49;
                float v = b2f(pu[t]);
                outF[((long)(b * 512 + n0 + n)) * 49 + pos] = 1.f / (1.f + __expf(-v));
            }
        }
    }
}

// ---------------------------------------------------------------------------

extern "C" void kernel_launch(void* const* d_in, const int* in_sizes, int n_in,
                              void* d_out, int out_size, void* d_ws, size_t ws_size,
                              hipStream_t stream)
{
    const float* input = (const float*)d_in[0];
    const int*   label = (const int*)d_in[1];
    const float* emb   = (const float*)d_in[2];
    const float* lw[5] = {(const float*)d_in[3], (const float*)d_in[5], (const float*)d_in[7],
                          (const float*)d_in[9], (const float*)d_in[11]};
    const float* lb[5] = {(const float*)d_in[4], (const float*)d_in[6], (const float*)d_in[8],
                          (const float*)d_in[10], (const float*)d_in[12]};
    const float* cmw[5] = {(const float*)d_in[13], (const float*)d_in[15], (const float*)d_in[17],
                           (const float*)d_in[19], (const float*)d_in[21]};
    const float* cmb[5] = {(const float*)d_in[14], (const float*)d_in[16], (const float*)d_in[18],
                           (const float*)d_in[20], (const float*)d_in[22]};
    const float* bng[4] = {(const float*)d_in[23], (const float*)d_in[25],
                           (const float*)d_in[27], (const float*)d_in[29]};
    const float* bnb[4] = {(const float*)d_in[24], (const float*)d_in[26],
                           (const float*)d_in[28], (const float*)d_in[30]};
    float* out = (float*)d_out;

    float* wsf   = (float*)d_ws;
    float* dynk  = wsf;
    float* stats = wsf + 1071104;
    const float* k1 = dynk;
    const float* k2 = dynk + 6144;
    const float* k3 = dynk + 137216;
    const float* k4 = dynk + 284672;
    const float* k5 = dynk + 808960;
    float* st1 = stats;
    float* st2 = stats + 128;
    float* st3 = stats + 384;
    float* st4 = stats + 896;

    bf16* wt  = (bf16*)((char*)d_ws + 4292096);
    bf16* wt2 = wt;
    bf16* wt3 = wt + 8192;
    bf16* wt4 = wt + 40960;
    bf16* wt5 = wt + 172032;
    bf16* S1  = (bf16*)((char*)d_ws + 5242880);    // y1/y2/y3/y4
    bf16* S2  = (bf16*)((char*)d_ws + 72351744);   // A2/A3/A4/A5

    prep_kernel<<<4186, 256, 0, stream>>>(label, emb,
        lw[0], lb[0], lw[1], lb[1], lw[2], lb[2], lw[3], lb[3], lw[4], lb[4],
        dynk, stats, out + 3211264);
    wt_kernel<<<424, 256, 0, stream>>>(cmw[1], cmw[2], cmw[3], cmw[4],
                                       wt2, wt3, wt4, wt5);

    // L1: fused (K=3) -> y1 [128,64,64,64] bf16 NHWC + st1
    fused_l1<3, 64, 4, 128, 64, 8><<<2048, 256, 0, stream>>>(
        input, k1, cmw[0], cmb[0], S1, st1, 8192);

    // L2
    dw_kernel<64, 4, 64, 32, 2, 1><<<16384, 256, 0, stream>>>(
        S1, st1, bng[0], bnb[0], k2, S2, 1.f / 524288.f);
    gemm_layer<64, 128, false><<<1024, 256, 0, stream>>>(
        S2, wt2, cmb[1], S1, st2, nullptr, 1024);

    // L3
    dw_kernel<128, 3, 32, 16, 2, 1><<<8192, 256, 0, stream>>>(
        S1, st2, bng[1], bnb[1], k3, S2, 1.f / 131072.f);
    gemm_layer<128, 256, false><<<512, 256, 0, stream>>>(
        S2, wt3, cmb[2], S1, st3, nullptr, 256);

    // L4
    dw_kernel<256, 4, 16, 8, 2, 1><<<4096, 256, 0, stream>>>(
        S1, st3, bng[2], bnb[2], k4, S2, 1.f / 32768.f);
    gemm_layer<256, 512, false><<<256, 256, 0, stream>>>(
        S2, wt4, cmb[3], S1, st4, nullptr, 64);

    // L5
    dw_kernel<512, 2, 8, 7, 1, 0><<<6272, 256, 0, stream>>>(
        S1, st4, bng[3], bnb[3], k5, S2, 1.f / 8192.f);
    gemm_layer<512, 512, true><<<196, 256, 0, stream>>>(
        S2, wt5, cmb[4], nullptr, nullptr, out, 49);
}